// Round 1
// baseline (622.955 us; speedup 1.0000x reference)
//
#include <hip/hip_runtime.h>

#define LATN 512
#define B1H  512
#define B2H  1024
#define NB   32
#define ACT_K 1536     // 512 (z) + 1024 (h2)
#define OUTSZ 33088
#define KOUT_OFF 16384
#define BIN_OFF  32768
#define BOUT_OFF 33024
#define NPIX 16384

typedef __attribute__((ext_vector_type(8))) short bf16x8;
typedef __attribute__((ext_vector_type(4))) float f32x4;

__device__ __forceinline__ short f2bf(float x) {
  unsigned u = __builtin_bit_cast(unsigned, x);
  u = (u + 0x7FFFu + ((u >> 16) & 1u)) >> 16;   // RNE
  return (short)u;
}

__device__ __forceinline__ bf16x8 cvt8(const float* __restrict__ p) {
  float4 a = *(const float4*)p;
  float4 b = *(const float4*)(p + 4);
  bf16x8 r;
  r[0] = f2bf(a.x); r[1] = f2bf(a.y); r[2] = f2bf(a.z); r[3] = f2bf(a.w);
  r[4] = f2bf(b.x); r[5] = f2bf(b.y); r[6] = f2bf(b.z); r[7] = f2bf(b.w);
  return r;
}

// XOR swizzle (bits 3..5 of ushort index) to break stride-128B bank conflicts
__device__ __forceinline__ int pswz(int px) { return ((px ^ (px >> 3)) & 7) << 3; }

// ---------------- stage 1: tiny MLPs (f32 vector) ----------------

// h1 = relu(lat @ b1_w1^T + b1_b1)   grid=32, block=512
__global__ void mlp1_kernel(const float* __restrict__ lat, const float* __restrict__ w1,
                            const float* __restrict__ b1, float* __restrict__ h1) {
  __shared__ __align__(16) float latS[LATN];
  int b = blockIdx.x, o = threadIdx.x;
  latS[o] = lat[b * LATN + o];
  __syncthreads();
  const float* wr = w1 + (size_t)o * LATN;
  float a0 = 0.f, a1 = 0.f, a2 = 0.f, a3 = 0.f;
  #pragma unroll 4
  for (int k = 0; k < LATN; k += 4) {
    float4 w = *(const float4*)(wr + k);
    float4 l4 = *(const float4*)(latS + k);
    a0 += w.x * l4.x; a1 += w.y * l4.y; a2 += w.z * l4.z; a3 += w.w * l4.w;
  }
  h1[b * B1H + o] = fmaxf(b1[o] + ((a0 + a1) + (a2 + a3)), 0.f);
}

// z = lat @ b1_ws^T + (h1 @ b1_w2^T + b1_b2) -> act[b][0..511]   grid=32, block=512
__global__ void mlp2_kernel(const float* __restrict__ lat, const float* __restrict__ h1,
                            const float* __restrict__ wsm, const float* __restrict__ w2,
                            const float* __restrict__ b2, float* __restrict__ act) {
  __shared__ __align__(16) float latS[LATN];
  __shared__ __align__(16) float hS[B1H];
  int b = blockIdx.x, o = threadIdx.x;
  latS[o] = lat[b * LATN + o];
  hS[o]   = h1[b * B1H + o];
  __syncthreads();
  const float* wsr = wsm + (size_t)o * LATN;
  const float* w2r = w2  + (size_t)o * B1H;
  float a0 = 0.f, a1 = 0.f, a2 = 0.f, a3 = 0.f;
  #pragma unroll 4
  for (int k = 0; k < LATN; k += 4) {
    float4 w = *(const float4*)(wsr + k);
    float4 l4 = *(const float4*)(latS + k);
    a0 += w.x * l4.x; a1 += w.y * l4.y; a2 += w.z * l4.z; a3 += w.w * l4.w;
    float4 w2v = *(const float4*)(w2r + k);
    float4 h4 = *(const float4*)(hS + k);
    a0 += w2v.x * h4.x; a1 += w2v.y * h4.y; a2 += w2v.z * h4.z; a3 += w2v.w * h4.w;
  }
  act[b * ACT_K + o] = b2[o] + ((a0 + a1) + (a2 + a3));
}

// h2 = relu(z @ b2_w1^T + b2_b1) -> act[b][512..1535]   grid=32, block=1024
__global__ void mlp3_kernel(const float* __restrict__ w1, const float* __restrict__ b1,
                            float* act) {
  __shared__ __align__(16) float zS[LATN];
  int b = blockIdx.x, o = threadIdx.x;
  if (o < LATN) zS[o] = act[b * ACT_K + o];
  __syncthreads();
  const float* wr = w1 + (size_t)o * LATN;
  float a0 = 0.f, a1 = 0.f, a2 = 0.f, a3 = 0.f;
  #pragma unroll 4
  for (int k = 0; k < LATN; k += 4) {
    float4 w = *(const float4*)(wr + k);
    float4 l4 = *(const float4*)(zS + k);
    a0 += w.x * l4.x; a1 += w.y * l4.y; a2 += w.z * l4.z; a3 += w.w * l4.w;
  }
  act[b * ACT_K + LATN + o] = fmaxf(b1[o] + ((a0 + a1) + (a2 + a3)), 0.f);
}

// ---------------- stage 2: ks = act @ [b2_ws | b2_w2]^T + b2_b2 ----------------
// M=32 (2 m-tiles), N=33088, K=1536. grid=517 (64 cols/block), block=256 (4 waves x 16 cols).
__global__ __launch_bounds__(256) void ks_gemm_kernel(
    const float* __restrict__ act,   // [32][1536]
    const float* __restrict__ wws,   // [33088][512]
    const float* __restrict__ ww2,   // [33088][1024]
    const float* __restrict__ bias,  // [33088]
    float* __restrict__ ks)          // [32][33088]
{
  const int wave = threadIdx.x >> 6, lane = threadIdx.x & 63;
  const int lrow = lane & 15, g = lane >> 4;
  const int col = blockIdx.x * 64 + wave * 16 + lrow;

  f32x4 acc0 = {0.f, 0.f, 0.f, 0.f};
  f32x4 acc1 = {0.f, 0.f, 0.f, 0.f};
  const float* a0 = act + (size_t)lrow * ACT_K;
  const float* a1 = act + (size_t)(lrow + 16) * ACT_K;
  const float* wsrow = wws + (size_t)col * LATN;
  const float* w2row = ww2 + (size_t)col * B2H;

  for (int k0 = 0; k0 < ACT_K; k0 += 32) {
    const int kk = k0 + g * 8;
    const float* wp = (k0 < LATN) ? (wsrow + kk) : (w2row + (kk - LATN));
    bf16x8 bfrag = cvt8(wp);
    bf16x8 af0 = cvt8(a0 + kk);
    bf16x8 af1 = cvt8(a1 + kk);
    acc0 = __builtin_amdgcn_mfma_f32_16x16x32_bf16(af0, bfrag, acc0, 0, 0, 0);
    acc1 = __builtin_amdgcn_mfma_f32_16x16x32_bf16(af1, bfrag, acc1, 0, 0, 0);
  }
  const float bv = bias[col];
  #pragma unroll
  for (int r = 0; r < 4; ++r) {
    const int m = g * 4 + r;   // D: row=(lane>>4)*4+r, col=lane&15
    ks[(size_t)m * OUTSZ + col]        = acc0[r] + bv;
    ks[(size_t)(m + 16) * OUTSZ + col] = acc1[r] + bv;
  }
}

// ---------------- stage 3: fused dynamic conv ----------------
// grid=(16,32): blockIdx.y=batch, blockIdx.x=1024-px strip. block=256 (4 waves).
__global__ __launch_bounds__(256, 2) void conv_fused_kernel(
    const float* __restrict__ x,    // [32][64][16384]
    const float* __restrict__ ks,   // [32][33088]
    float* __restrict__ out)        // [32][64][16384]
{
  __shared__ __align__(16) unsigned short Xl[64 * 64];    // [px][f]  bf16, swizzled
  __shared__ __align__(16) unsigned short Hl[64 * 256];   // [px][h]  bf16, swizzled

  const int tid = threadIdx.x;
  const int wave = tid >> 6, lane = tid & 63;
  const int lrow = lane & 15, g = lane >> 4;
  const int b = blockIdx.y;
  const float* ksb = ks + (size_t)b * OUTSZ;
  const float* xb  = x  + (size_t)b * 64 * NPIX;
  float* ob        = out + (size_t)b * 64 * NPIX;

  // Hoisted MFMA A-fragments. C1: A=Kin (wave owns h rows [64w,64w+64)).
  bf16x8 kinF[4][2];
  #pragma unroll
  for (int mt = 0; mt < 4; ++mt)
    #pragma unroll
    for (int kst = 0; kst < 2; ++kst) {
      const int h = 64 * wave + mt * 16 + lrow;
      kinF[mt][kst] = cvt8(ksb + (size_t)h * 64 + kst * 32 + g * 8);
    }
  // C2: A=Kout (wave owns o rows [16w,16w+16)).
  bf16x8 koutF[8];
  {
    const int o = 16 * wave + lrow;
    #pragma unroll
    for (int kst = 0; kst < 8; ++kst)
      koutF[kst] = cvt8(ksb + KOUT_OFF + (size_t)o * 256 + kst * 32 + g * 8);
  }
  float bin[4][4];
  #pragma unroll
  for (int mt = 0; mt < 4; ++mt)
    #pragma unroll
    for (int r = 0; r < 4; ++r)
      bin[mt][r] = ksb[BIN_OFF + 64 * wave + mt * 16 + g * 4 + r];
  float bout[4];
  #pragma unroll
  for (int r = 0; r < 4; ++r)
    bout[r] = ksb[BOUT_OFF + 16 * wave + g * 4 + r];

  const int fstage = tid >> 2;   // 0..63: f row this thread stages
  const int pq = tid & 3;        // px quarter

  for (int c = 0; c < 16; ++c) {
    const int p0 = blockIdx.x * 1024 + c * 64;
    __syncthreads();   // prior C1 done with Xl, prior C2 done with Hl
    // ---- stage X tile: global f32 -> bf16 LDS [px][f] (transposed, swizzled) ----
    {
      const float* xr = xb + (size_t)fstage * NPIX + p0 + pq * 16;
      #pragma unroll
      for (int i = 0; i < 4; ++i) {
        float4 v = *(const float4*)(xr + i * 4);
        const int pxb = pq * 16 + i * 4;
        Xl[(pxb + 0) * 64 + (fstage ^ pswz(pxb + 0))] = (unsigned short)f2bf(v.x);
        Xl[(pxb + 1) * 64 + (fstage ^ pswz(pxb + 1))] = (unsigned short)f2bf(v.y);
        Xl[(pxb + 2) * 64 + (fstage ^ pswz(pxb + 2))] = (unsigned short)f2bf(v.z);
        Xl[(pxb + 3) * 64 + (fstage ^ pswz(pxb + 3))] = (unsigned short)f2bf(v.w);
      }
    }
    __syncthreads();
    // ---- C1: H[256][64px] = relu(Kin @ X + b_in) ----
    f32x4 accH[4][4];
    #pragma unroll
    for (int mt = 0; mt < 4; ++mt)
      #pragma unroll
      for (int nt = 0; nt < 4; ++nt)
        accH[mt][nt] = (f32x4){0.f, 0.f, 0.f, 0.f};
    #pragma unroll
    for (int kst = 0; kst < 2; ++kst)
      #pragma unroll
      for (int nt = 0; nt < 4; ++nt) {
        const int px = nt * 16 + lrow;
        bf16x8 xf = *(const bf16x8*)&Xl[px * 64 + ((kst * 32 + g * 8) ^ pswz(px))];
        #pragma unroll
        for (int mt = 0; mt < 4; ++mt)
          accH[mt][nt] = __builtin_amdgcn_mfma_f32_16x16x32_bf16(kinF[mt][kst], xf, accH[mt][nt], 0, 0, 0);
      }
    // write H (relu+bias, pack pairs) into Hl[px][h]
    #pragma unroll
    for (int mt = 0; mt < 4; ++mt) {
      const int hbase = 64 * wave + mt * 16 + g * 4;
      #pragma unroll
      for (int nt = 0; nt < 4; ++nt) {
        const int px = nt * 16 + lrow;
        float h0 = fmaxf(accH[mt][nt][0] + bin[mt][0], 0.f);
        float h1 = fmaxf(accH[mt][nt][1] + bin[mt][1], 0.f);
        float h2 = fmaxf(accH[mt][nt][2] + bin[mt][2], 0.f);
        float h3 = fmaxf(accH[mt][nt][3] + bin[mt][3], 0.f);
        unsigned p01 = (unsigned)(unsigned short)f2bf(h0) | ((unsigned)(unsigned short)f2bf(h1) << 16);
        unsigned p23 = (unsigned)(unsigned short)f2bf(h2) | ((unsigned)(unsigned short)f2bf(h3) << 16);
        *(unsigned*)&Hl[px * 256 + ((hbase + 0) ^ pswz(px))] = p01;
        *(unsigned*)&Hl[px * 256 + ((hbase + 2) ^ pswz(px))] = p23;
      }
    }
    __syncthreads();
    // ---- C2: OUT[64][64px] = Kout @ H + b_out ----
    f32x4 accO[4];
    #pragma unroll
    for (int nt = 0; nt < 4; ++nt) accO[nt] = (f32x4){0.f, 0.f, 0.f, 0.f};
    #pragma unroll
    for (int kst = 0; kst < 8; ++kst)
      #pragma unroll
      for (int nt = 0; nt < 4; ++nt) {
        const int px = nt * 16 + lrow;
        bf16x8 hf = *(const bf16x8*)&Hl[px * 256 + ((kst * 32 + g * 8) ^ pswz(px))];
        accO[nt] = __builtin_amdgcn_mfma_f32_16x16x32_bf16(koutF[kst], hf, accO[nt], 0, 0, 0);
      }
    #pragma unroll
    for (int nt = 0; nt < 4; ++nt) {
      const int px = p0 + nt * 16 + lrow;
      #pragma unroll
      for (int r = 0; r < 4; ++r) {
        const int o = 16 * wave + g * 4 + r;
        ob[(size_t)o * NPIX + px] = accO[nt][r] + bout[r];
      }
    }
  }
}

extern "C" void kernel_launch(void* const* d_in, const int* in_sizes, int n_in,
                              void* d_out, int out_size, void* d_ws, size_t ws_size,
                              hipStream_t stream) {
  const float* x     = (const float*)d_in[0];
  const float* lat   = (const float*)d_in[1];
  const float* b1_w1 = (const float*)d_in[2];
  const float* b1_b1 = (const float*)d_in[3];
  const float* b1_w2 = (const float*)d_in[4];
  const float* b1_b2 = (const float*)d_in[5];
  const float* b1_ws = (const float*)d_in[6];
  const float* b2_w1 = (const float*)d_in[7];
  const float* b2_b1 = (const float*)d_in[8];
  const float* b2_w2 = (const float*)d_in[9];
  const float* b2_b2 = (const float*)d_in[10];
  const float* b2_ws = (const float*)d_in[11];
  float* out = (float*)d_out;

  float* ws   = (float*)d_ws;
  float* h1   = ws;                       // [32][512]
  float* act  = ws + 16384;               // [32][1536] = [z | h2]
  float* ksb  = ws + 16384 + NB * ACT_K;  // [32][33088]

  mlp1_kernel<<<NB, 512, 0, stream>>>(lat, b1_w1, b1_b1, h1);
  mlp2_kernel<<<NB, 512, 0, stream>>>(lat, h1, b1_ws, b1_w2, b1_b2, act);
  mlp3_kernel<<<NB, 1024, 0, stream>>>(b2_w1, b2_b1, act);
  ks_gemm_kernel<<<OUTSZ / 64, 256, 0, stream>>>(act, b2_ws, b2_w2, b2_b2, ksb);
  conv_fused_kernel<<<dim3(16, 32), 256, 0, stream>>>(x, ksb, out);
}

// Round 2
// 461.198 us; speedup vs baseline: 1.3507x; 1.3507x over previous
//
#include <hip/hip_runtime.h>

#define LATN 512
#define B1H  512
#define B2H  1024
#define NB   32
#define ACT_K 1536     // 512 (z) + 1024 (h2)
#define OUTSZ 33088
#define KOUT_OFF 16384
#define BIN_OFF  32768
#define BOUT_OFF 33024
#define NPIX 16384

typedef __attribute__((ext_vector_type(8))) short bf16x8;
typedef __attribute__((ext_vector_type(4))) float f32x4;

__device__ __forceinline__ short f2bf(float x) {
  unsigned u = __builtin_bit_cast(unsigned, x);
  u = (u + 0x7FFFu + ((u >> 16) & 1u)) >> 16;   // RNE
  return (short)u;
}

__device__ __forceinline__ bf16x8 cvt8(const float* __restrict__ p) {
  float4 a = *(const float4*)p;
  float4 b = *(const float4*)(p + 4);
  bf16x8 r;
  r[0] = f2bf(a.x); r[1] = f2bf(a.y); r[2] = f2bf(a.z); r[3] = f2bf(a.w);
  r[4] = f2bf(b.x); r[5] = f2bf(b.y); r[6] = f2bf(b.z); r[7] = f2bf(b.w);
  return r;
}

__device__ __forceinline__ void fma4(f32x4& c, float4 w, float4 l) {
  c[0] = fmaf(w.x, l.x, c[0]);
  c[1] = fmaf(w.y, l.y, c[1]);
  c[2] = fmaf(w.z, l.z, c[2]);
  c[3] = fmaf(w.w, l.w, c[3]);
}

// XOR swizzle (bits 3..5 of ushort index) to break stride-128B bank conflicts
__device__ __forceinline__ int pswz(int px) { return ((px ^ (px >> 3)) & 7) << 3; }

// ---------------- stage 1: tiny MLPs (f32 vector, 4 lanes/output) ----------------
// layout: 64 outputs/block, lane>>2 = local output, lane&3 = K quarter (128 each)

// h1 = relu(lat @ b1_w1^T + b1)   grid=(8,32) block=256
__global__ __launch_bounds__(256) void mlp_a(const float* __restrict__ lat,
                                             const float* __restrict__ w1,
                                             const float* __restrict__ b1,
                                             float* __restrict__ h1) {
  const int t = threadIdx.x, lane = t & 63, wv = t >> 6;
  const int outL = wv * 16 + (lane >> 2), part = lane & 3;
  const int b = blockIdx.y, out = blockIdx.x * 64 + outL;
  const float4* W = (const float4*)(w1 + (size_t)out * LATN + part * 128);
  const float4* L = (const float4*)(lat + (size_t)b * LATN + part * 128);
  f32x4 c0 = {0,0,0,0}, c1 = {0,0,0,0}, c2 = {0,0,0,0}, c3 = {0,0,0,0};
  #pragma unroll
  for (int i = 0; i < 32; i += 4) {
    fma4(c0, W[i], L[i]); fma4(c1, W[i+1], L[i+1]);
    fma4(c2, W[i+2], L[i+2]); fma4(c3, W[i+3], L[i+3]);
  }
  c0 += c1; c2 += c3; c0 += c2;
  float v = (c0[0] + c0[1]) + (c0[2] + c0[3]);
  v += __shfl_xor(v, 1); v += __shfl_xor(v, 2);
  if (part == 0) h1[b * B1H + out] = fmaxf(v + b1[out], 0.f);
}

// z = lat@ws^T + h1@w2^T + b2 -> zf (f32) and actb[b][0..511] (bf16)   grid=(8,32)
__global__ __launch_bounds__(256) void mlp_b(const float* __restrict__ lat,
                                             const float* __restrict__ h1,
                                             const float* __restrict__ wsm,
                                             const float* __restrict__ w2,
                                             const float* __restrict__ b2,
                                             float* __restrict__ zf,
                                             unsigned short* __restrict__ actb) {
  const int t = threadIdx.x, lane = t & 63, wv = t >> 6;
  const int outL = wv * 16 + (lane >> 2), part = lane & 3;
  const int b = blockIdx.y, out = blockIdx.x * 64 + outL;
  const float4* Ws = (const float4*)(wsm + (size_t)out * LATN + part * 128);
  const float4* W2 = (const float4*)(w2  + (size_t)out * B1H  + part * 128);
  const float4* L  = (const float4*)(lat + (size_t)b * LATN + part * 128);
  const float4* H  = (const float4*)(h1  + (size_t)b * B1H  + part * 128);
  f32x4 c0 = {0,0,0,0}, c1 = {0,0,0,0}, c2 = {0,0,0,0}, c3 = {0,0,0,0};
  #pragma unroll
  for (int i = 0; i < 32; i += 2) {
    fma4(c0, Ws[i], L[i]);   fma4(c1, Ws[i+1], L[i+1]);
    fma4(c2, W2[i], H[i]);   fma4(c3, W2[i+1], H[i+1]);
  }
  c0 += c1; c2 += c3; c0 += c2;
  float v = (c0[0] + c0[1]) + (c0[2] + c0[3]);
  v += __shfl_xor(v, 1); v += __shfl_xor(v, 2);
  if (part == 0) {
    v += b2[out];
    zf[b * LATN + out] = v;
    actb[(size_t)b * ACT_K + out] = (unsigned short)f2bf(v);
  }
}

// h2 = relu(z @ b2_w1^T + b2_b1) -> actb[b][512..1535] (bf16)   grid=(16,32)
__global__ __launch_bounds__(256) void mlp_c(const float* __restrict__ zf,
                                             const float* __restrict__ w1,
                                             const float* __restrict__ b1,
                                             unsigned short* __restrict__ actb) {
  const int t = threadIdx.x, lane = t & 63, wv = t >> 6;
  const int outL = wv * 16 + (lane >> 2), part = lane & 3;
  const int b = blockIdx.y, out = blockIdx.x * 64 + outL;
  const float4* W = (const float4*)(w1 + (size_t)out * LATN + part * 128);
  const float4* Z = (const float4*)(zf + (size_t)b * LATN + part * 128);
  f32x4 c0 = {0,0,0,0}, c1 = {0,0,0,0}, c2 = {0,0,0,0}, c3 = {0,0,0,0};
  #pragma unroll
  for (int i = 0; i < 32; i += 4) {
    fma4(c0, W[i], Z[i]); fma4(c1, W[i+1], Z[i+1]);
    fma4(c2, W[i+2], Z[i+2]); fma4(c3, W[i+3], Z[i+3]);
  }
  c0 += c1; c2 += c3; c0 += c2;
  float v = (c0[0] + c0[1]) + (c0[2] + c0[3]);
  v += __shfl_xor(v, 1); v += __shfl_xor(v, 2);
  if (part == 0)
    actb[(size_t)b * ACT_K + LATN + out] = (unsigned short)f2bf(fmaxf(v + b1[out], 0.f));
}

// ---------------- stage 2: ks = act @ [b2_ws | b2_w2]^T + b2_b2 ----------------
// grid = OUTSZ/16 = 2068 blocks, block=256. Each block: 16 cols; wave w takes
// K-chunk [384w, 384w+384); cross-wave LDS reduce at the end. 32 waves/CU.
__global__ __launch_bounds__(256) void ks_gemm2(
    const unsigned short* __restrict__ actb,  // [32][1536] bf16
    const float* __restrict__ wws,            // [33088][512]
    const float* __restrict__ ww2,            // [33088][1024]
    const float* __restrict__ bias,           // [33088]
    float* __restrict__ ks)                   // [32][33088]
{
  __shared__ __align__(16) float red[4][64][8];
  const int t = threadIdx.x, lane = t & 63, wv = t >> 6;
  const int lrow = lane & 15, g = lane >> 4;
  const int col = blockIdx.x * 16 + lrow;

  const float* wsrow = wws + (size_t)col * LATN;
  const float* w2row = ww2 + (size_t)col * B2H;
  const unsigned short* a0 = actb + (size_t)lrow * ACT_K;
  const unsigned short* a1 = a0 + (size_t)16 * ACT_K;

  f32x4 acc0 = {0,0,0,0};
  f32x4 acc1 = {0,0,0,0};
  const int kbase = wv * 384;
  #pragma unroll 4
  for (int it = 0; it < 12; ++it) {
    const int kk = kbase + it * 32 + g * 8;
    const float* wp = (kk < LATN) ? (wsrow + kk) : (w2row + (kk - LATN));
    bf16x8 bfrag = cvt8(wp);
    bf16x8 af0 = *(const bf16x8*)(a0 + kk);
    bf16x8 af1 = *(const bf16x8*)(a1 + kk);
    acc0 = __builtin_amdgcn_mfma_f32_16x16x32_bf16(af0, bfrag, acc0, 0, 0, 0);
    acc1 = __builtin_amdgcn_mfma_f32_16x16x32_bf16(af1, bfrag, acc1, 0, 0, 0);
  }
  *(f32x4*)&red[wv][lane][0] = acc0;
  *(f32x4*)&red[wv][lane][4] = acc1;
  __syncthreads();
  if (wv == 0) {
    const float bv = bias[col];
    #pragma unroll
    for (int r = 0; r < 8; ++r) {
      float s = (red[0][lane][r] + red[1][lane][r]) + (red[2][lane][r] + red[3][lane][r]);
      const int m = (r < 4) ? (g * 4 + r) : (16 + g * 4 + (r - 4));
      ks[(size_t)m * OUTSZ + col] = s + bv;   // D: row=(lane>>4)*4+r, col=lane&15
    }
  }
}

// ---------------- stage 3: fused dynamic conv ----------------
// grid=(16,32): blockIdx.y=batch, blockIdx.x=1024-px strip. block=256 (4 waves).
__global__ __launch_bounds__(256, 2) void conv_fused_kernel(
    const float* __restrict__ x,    // [32][64][16384]
    const float* __restrict__ ks,   // [32][33088]
    float* __restrict__ out)        // [32][64][16384]
{
  __shared__ __align__(16) unsigned short Xl[64 * 64];    // [px][f]  bf16, swizzled
  __shared__ __align__(16) unsigned short Hl[64 * 256];   // [px][h]  bf16, swizzled

  const int tid = threadIdx.x;
  const int wave = tid >> 6, lane = tid & 63;
  const int lrow = lane & 15, g = lane >> 4;
  const int b = blockIdx.y;
  const float* ksb = ks + (size_t)b * OUTSZ;
  const float* xb  = x  + (size_t)b * 64 * NPIX;
  float* ob        = out + (size_t)b * 64 * NPIX;

  // Hoisted MFMA A-fragments. C1: A=Kin (wave owns h rows [64w,64w+64)).
  bf16x8 kinF[4][2];
  #pragma unroll
  for (int mt = 0; mt < 4; ++mt)
    #pragma unroll
    for (int kst = 0; kst < 2; ++kst) {
      const int h = 64 * wave + mt * 16 + lrow;
      kinF[mt][kst] = cvt8(ksb + (size_t)h * 64 + kst * 32 + g * 8);
    }
  // C2: A=Kout (wave owns o rows [16w,16w+16)).
  bf16x8 koutF[8];
  {
    const int o = 16 * wave + lrow;
    #pragma unroll
    for (int kst = 0; kst < 8; ++kst)
      koutF[kst] = cvt8(ksb + KOUT_OFF + (size_t)o * 256 + kst * 32 + g * 8);
  }
  float bin[4][4];
  #pragma unroll
  for (int mt = 0; mt < 4; ++mt)
    #pragma unroll
    for (int r = 0; r < 4; ++r)
      bin[mt][r] = ksb[BIN_OFF + 64 * wave + mt * 16 + g * 4 + r];
  float bout[4];
  #pragma unroll
  for (int r = 0; r < 4; ++r)
    bout[r] = ksb[BOUT_OFF + 16 * wave + g * 4 + r];

  const int fstage = tid >> 2;   // 0..63: f row this thread stages
  const int pq = tid & 3;        // px quarter

  for (int c = 0; c < 16; ++c) {
    const int p0 = blockIdx.x * 1024 + c * 64;
    __syncthreads();   // prior C1 done with Xl, prior C2 done with Hl
    // ---- stage X tile: global f32 -> bf16 LDS [px][f] (transposed, swizzled) ----
    {
      const float* xr = xb + (size_t)fstage * NPIX + p0 + pq * 16;
      #pragma unroll
      for (int i = 0; i < 4; ++i) {
        float4 v = *(const float4*)(xr + i * 4);
        const int pxb = pq * 16 + i * 4;
        Xl[(pxb + 0) * 64 + (fstage ^ pswz(pxb + 0))] = (unsigned short)f2bf(v.x);
        Xl[(pxb + 1) * 64 + (fstage ^ pswz(pxb + 1))] = (unsigned short)f2bf(v.y);
        Xl[(pxb + 2) * 64 + (fstage ^ pswz(pxb + 2))] = (unsigned short)f2bf(v.z);
        Xl[(pxb + 3) * 64 + (fstage ^ pswz(pxb + 3))] = (unsigned short)f2bf(v.w);
      }
    }
    __syncthreads();
    // ---- C1: H[256][64px] = relu(Kin @ X + b_in) ----
    f32x4 accH[4][4];
    #pragma unroll
    for (int mt = 0; mt < 4; ++mt)
      #pragma unroll
      for (int nt = 0; nt < 4; ++nt)
        accH[mt][nt] = (f32x4){0.f, 0.f, 0.f, 0.f};
    #pragma unroll
    for (int kst = 0; kst < 2; ++kst)
      #pragma unroll
      for (int nt = 0; nt < 4; ++nt) {
        const int px = nt * 16 + lrow;
        bf16x8 xf = *(const bf16x8*)&Xl[px * 64 + ((kst * 32 + g * 8) ^ pswz(px))];
        #pragma unroll
        for (int mt = 0; mt < 4; ++mt)
          accH[mt][nt] = __builtin_amdgcn_mfma_f32_16x16x32_bf16(kinF[mt][kst], xf, accH[mt][nt], 0, 0, 0);
      }
    // write H (relu+bias, pack pairs) into Hl[px][h]
    #pragma unroll
    for (int mt = 0; mt < 4; ++mt) {
      const int hbase = 64 * wave + mt * 16 + g * 4;
      #pragma unroll
      for (int nt = 0; nt < 4; ++nt) {
        const int px = nt * 16 + lrow;
        float h0 = fmaxf(accH[mt][nt][0] + bin[mt][0], 0.f);
        float h1 = fmaxf(accH[mt][nt][1] + bin[mt][1], 0.f);
        float h2 = fmaxf(accH[mt][nt][2] + bin[mt][2], 0.f);
        float h3 = fmaxf(accH[mt][nt][3] + bin[mt][3], 0.f);
        unsigned p01 = (unsigned)(unsigned short)f2bf(h0) | ((unsigned)(unsigned short)f2bf(h1) << 16);
        unsigned p23 = (unsigned)(unsigned short)f2bf(h2) | ((unsigned)(unsigned short)f2bf(h3) << 16);
        *(unsigned*)&Hl[px * 256 + ((hbase + 0) ^ pswz(px))] = p01;
        *(unsigned*)&Hl[px * 256 + ((hbase + 2) ^ pswz(px))] = p23;
      }
    }
    __syncthreads();
    // ---- C2: OUT[64][64px] = Kout @ H + b_out ----
    f32x4 accO[4];
    #pragma unroll
    for (int nt = 0; nt < 4; ++nt) accO[nt] = (f32x4){0.f, 0.f, 0.f, 0.f};
    #pragma unroll
    for (int kst = 0; kst < 8; ++kst)
      #pragma unroll
      for (int nt = 0; nt < 4; ++nt) {
        const int px = nt * 16 + lrow;
        bf16x8 hf = *(const bf16x8*)&Hl[px * 256 + ((kst * 32 + g * 8) ^ pswz(px))];
        accO[nt] = __builtin_amdgcn_mfma_f32_16x16x32_bf16(koutF[kst], hf, accO[nt], 0, 0, 0);
      }
    #pragma unroll
    for (int nt = 0; nt < 4; ++nt) {
      const int px = p0 + nt * 16 + lrow;
      #pragma unroll
      for (int r = 0; r < 4; ++r) {
        const int o = 16 * wave + g * 4 + r;
        ob[(size_t)o * NPIX + px] = accO[nt][r] + bout[r];
      }
    }
  }
}

extern "C" void kernel_launch(void* const* d_in, const int* in_sizes, int n_in,
                              void* d_out, int out_size, void* d_ws, size_t ws_size,
                              hipStream_t stream) {
  const float* x     = (const float*)d_in[0];
  const float* lat   = (const float*)d_in[1];
  const float* b1_w1 = (const float*)d_in[2];
  const float* b1_b1 = (const float*)d_in[3];
  const float* b1_w2 = (const float*)d_in[4];
  const float* b1_b2 = (const float*)d_in[5];
  const float* b1_ws = (const float*)d_in[6];
  const float* b2_w1 = (const float*)d_in[7];
  const float* b2_b1 = (const float*)d_in[8];
  const float* b2_w2 = (const float*)d_in[9];
  const float* b2_b2 = (const float*)d_in[10];
  const float* b2_ws = (const float*)d_in[11];
  float* out = (float*)d_out;

  float* ws = (float*)d_ws;
  float* h1           = ws;                    // [32][512] f32
  float* zf           = ws + 16384;            // [32][512] f32
  unsigned short* actb = (unsigned short*)(ws + 32768);  // [32][1536] bf16 (24576 floats)
  float* ksb          = ws + 32768 + 24576;    // [32][33088] f32

  mlp_a<<<dim3(8, NB), 256, 0, stream>>>(lat, b1_w1, b1_b1, h1);
  mlp_b<<<dim3(8, NB), 256, 0, stream>>>(lat, h1, b1_ws, b1_w2, b1_b2, zf, actb);
  mlp_c<<<dim3(16, NB), 256, 0, stream>>>(zf, b2_w1, b2_b1, actb);
  ks_gemm2<<<OUTSZ / 16, 256, 0, stream>>>(actb, b2_ws, b2_w2, b2_b2, ksb);
  conv_fused_kernel<<<dim3(16, NB), 256, 0, stream>>>(x, ksb, out);
}